// Round 5
// baseline (1810.824 us; speedup 1.0000x reference)
//
#include <hip/hip_runtime.h>
#include <hip/hip_bf16.h>

typedef __bf16 bf16_t;
typedef bf16_t bf16x8 __attribute__((ext_vector_type(8)));
typedef float f32x4 __attribute__((ext_vector_type(4)));
typedef unsigned short u16;
typedef unsigned int u32;

static __device__ __forceinline__ u16 f2bf(float f) {
    __hip_bfloat16 h = __float2bfloat16(f);
    return __builtin_bit_cast(u16, h);
}
static __device__ __forceinline__ float bf2f(u16 u) {
    u32 x = ((u32)u) << 16;
    return __builtin_bit_cast(float, x);
}
static __device__ __forceinline__ float lo32(u32 p) { return __builtin_bit_cast(float, p << 16); }
static __device__ __forceinline__ float hi32(u32 p) { return __builtin_bit_cast(float, p & 0xffff0000u); }
static __device__ __forceinline__ float softthr(float v, float l) {
    return copysignf(fmaxf(fabsf(v) - l, 0.0f), v);
}

// ---- prep: Dict copy to out[2], Dnegb = -Dict bf16 [128][512], DictT bf16 [512][128] ----
__global__ __launch_bounds__(256) void prep_dict(const float* __restrict__ Dict,
                                                 float* __restrict__ outd,
                                                 u16* __restrict__ Dnegb,
                                                 u16* __restrict__ DictT)
{
    int i = blockIdx.x * 256 + threadIdx.x;   // 65536 total
    float v = Dict[i];
    outd[i] = v;
    Dnegb[i] = f2bf(-v);
    int d = i >> 9, a = i & 511;
    DictT[(a << 7) + d] = f2bf(v);
}

// ---- fused LISTA, rank-128 factored, 32 pixels/block, 512 thr (16 thr/px) ----
// z_{t+1} = ST( z_t + (x - z_t @ Dict^T) @ Dict / L ),  z_0 = ST(x @ Dict)
// GEMM1: acc1 = x + z_bf @ (-Dict^T)  [M=32, N=128, K=512]  (16x32 tile/wave)
// GEMM2: accz += r @ Dict             [M=32, N=512, K=128]  (16x128 tile/wave)
// accz (fp32, 32 regs/thread) IS z — never rounded across iterations.
__global__ __launch_bounds__(512, 4)
void lista_main(const float* __restrict__ x,
                const float* __restrict__ alpha,
                const float* __restrict__ Lp,
                const int* __restrict__ nip,
                const u16* __restrict__ Dnegb,   // -Dict bf16 [128][512]
                const u16* __restrict__ DictT,   // Dict^T bf16 [512][128]
                float* __restrict__ outz,        // [32][512][1024]
                float* __restrict__ outr)        // [32][128][1024]
{
    __shared__ __align__(16) u16 zl[32 * 512];   // 32 KB: z bf16, swizzled
    __shared__ __align__(16) u16 rl[32 * 128];   // 8 KB: r bf16, swizzled (x at iter 0)

    const int t = threadIdx.x;
    const int lane = t & 63;
    const int l15 = lane & 15;
    const int lg = lane >> 4;          // 0..3
    const int wave = t >> 6;
    const int wm = wave >> 2;          // 0..1 : pixel half (16 rows each)
    const int wn = wave & 3;           // 0..3
    const int rb = wm << 4;            // wave row (pixel) base
    const int cb1 = wn << 5;           // GEMM1 col base (dims, 32/wave)
    const int cb2 = wn << 7;           // GEMM2 col base (atoms, 128/wave)
    const int bb = blockIdx.x >> 5;            // batch
    const int hw0 = (blockIdx.x & 31) << 5;    // 32-pixel base
    const float invL = 1.0f / Lp[0];
    const int niter = nip[0];

    // ---- stage x -> rl bf16 swizzled (iter-0 GEMM2 A operand, unscaled) ----
    for (int i = t; i < 32 * 128; i += 512) {
        int d = i >> 5, r = i & 31;
        float v = x[((bb * 128 + d) << 10) + hw0 + r];
        rl[((r << 7) + d) ^ ((r & 7) << 3)] = f2bf(v);
    }

    // ---- x register copy at GEMM1 C positions, packed bf16 pairs (4 regs) ----
    u32 xpk[2][2];
#pragma unroll
    for (int nt = 0; nt < 2; ++nt) {
        int col = cb1 + nt * 16 + l15;
        const float* xp = &x[((bb * 128 + col) << 10) + hw0 + rb + lg * 4];
#pragma unroll
        for (int h = 0; h < 2; ++h)
            xpk[nt][h] = (u32)f2bf(xp[h * 2]) | ((u32)f2bf(xp[h * 2 + 1]) << 16);
    }

    // ---- thresholds alpha/L at C rows, packed (2 regs) ----
    u32 thp[2];
    {
        const float* ap = &alpha[hw0 + rb + lg * 4];
#pragma unroll
        for (int h = 0; h < 2; ++h)
            thp[h] = (u32)f2bf(ap[h * 2] * invL) | ((u32)f2bf(ap[h * 2 + 1] * invL) << 16);
    }
    __syncthreads();

    // GEMM1: acc1 = x + z_bf @ (-Dict^T)   [16x32 tile/wave, K=512]
    auto run_gemm1 = [&](f32x4 (&acc1)[2]) {
#pragma unroll
        for (int nt = 0; nt < 2; ++nt) {
            acc1[nt][0] = lo32(xpk[nt][0]);
            acc1[nt][1] = hi32(xpk[nt][0]);
            acc1[nt][2] = lo32(xpk[nt][1]);
            acc1[nt][3] = hi32(xpk[nt][1]);
        }
        const u16* b0 = &Dnegb[((cb1 + l15) << 9) + lg * 8];
#pragma unroll
        for (int kt = 0; kt < 16; ++kt) {
            const int k0 = kt * 32 + lg * 8;
            bf16x8 Bf0 = *reinterpret_cast<const bf16x8*>(b0 + kt * 32);
            bf16x8 Bf1 = *reinterpret_cast<const bf16x8*>(b0 + (16 << 9) + kt * 32);
            int row = rb + l15;
            bf16x8 Af = *reinterpret_cast<const bf16x8*>(&zl[((row << 9) + k0) ^ ((row & 7) << 3)]);
            acc1[0] = __builtin_amdgcn_mfma_f32_16x16x32_bf16(Af, Bf0, acc1[0], 0, 0, 0);
            acc1[1] = __builtin_amdgcn_mfma_f32_16x16x32_bf16(Af, Bf1, acc1[1], 0, 0, 0);
        }
    };

    f32x4 accz[8];
#pragma unroll
    for (int nt = 0; nt < 8; ++nt)
        accz[nt] = f32x4{0.f, 0.f, 0.f, 0.f};

    for (int it = 0; it <= niter; ++it) {
        if (it > 0) {
            f32x4 acc1[2];
            run_gemm1(acc1);
            // r = acc1 * invL -> rl
#pragma unroll
            for (int nt = 0; nt < 2; ++nt) {
                int col = cb1 + nt * 16 + l15;
#pragma unroll
                for (int rr = 0; rr < 4; ++rr) {
                    int row = rb + lg * 4 + rr;
                    rl[((row << 7) + col) ^ ((row & 7) << 3)] = f2bf(acc1[nt][rr] * invL);
                }
            }
            __syncthreads();   // GEMM1 zl reads done; rl complete
        }

        // ---- GEMM2: accz += rl @ Dict   [16x128 tile/wave, K=128] ----
        const u16* c0 = &DictT[((cb2 + l15) << 7) + lg * 8];
#pragma unroll
        for (int kt = 0; kt < 4; ++kt) {
            const int k0 = kt * 32 + lg * 8;
            int row = rb + l15;
            bf16x8 Af = *reinterpret_cast<const bf16x8*>(&rl[((row << 7) + k0) ^ ((row & 7) << 3)]);
            __builtin_amdgcn_s_setprio(1);
#pragma unroll
            for (int nt = 0; nt < 8; ++nt) {
                bf16x8 Cf = *reinterpret_cast<const bf16x8*>(c0 + (nt << 11) + kt * 32);
                accz[nt] = __builtin_amdgcn_mfma_f32_16x16x32_bf16(Af, Cf, accz[nt], 0, 0, 0);
            }
            __builtin_amdgcn_s_setprio(0);
        }

        // ---- soft-threshold in place; write z bf16 to zl ----
        {
            const float t0 = lo32(thp[0]), t1 = hi32(thp[0]);
            const float t2 = lo32(thp[1]), t3 = hi32(thp[1]);
#pragma unroll
            for (int nt = 0; nt < 8; ++nt) {
                int col = cb2 + nt * 16 + l15;
                f32x4 a = accz[nt];
                a[0] = softthr(a[0], t0);
                a[1] = softthr(a[1], t1);
                a[2] = softthr(a[2], t2);
                a[3] = softthr(a[3], t3);
                accz[nt] = a;
#pragma unroll
                for (int rr = 0; rr < 4; ++rr) {
                    int row = rb + lg * 4 + rr;
                    zl[((row << 9) + col) ^ ((row & 7) << 3)] = f2bf(a[rr]);
                }
            }
        }
        __syncthreads();
    }

    // ---- final GEMM1: x_recon = x - acc1 ----
    f32x4 acc1[2];
    run_gemm1(acc1);

    // ---- store z from zl (nontemporal, coalesced 128B segments) ----
    for (int i = t; i < 32 * 512; i += 512) {
        int a = i >> 5, r = i & 31;
        float zv = bf2f(zl[((r << 9) + a) ^ ((r & 7) << 3)]);
        __builtin_nontemporal_store(zv, &outz[((bb * 512 + a) << 10) + hw0 + r]);
    }
    __syncthreads();   // zl reads done before overwrite

    // ---- stage x_recon fp32 [32][128] swizzled in zl front ----
    float* wf = reinterpret_cast<float*>(zl);
#pragma unroll
    for (int nt = 0; nt < 2; ++nt) {
        int col = cb1 + nt * 16 + l15;
        f32x4 xr;
        xr[0] = lo32(xpk[nt][0]) - acc1[nt][0];
        xr[1] = hi32(xpk[nt][0]) - acc1[nt][1];
        xr[2] = lo32(xpk[nt][1]) - acc1[nt][2];
        xr[3] = hi32(xpk[nt][1]) - acc1[nt][3];
#pragma unroll
        for (int rr = 0; rr < 4; ++rr) {
            int row = rb + lg * 4 + rr;
            wf[((row << 7) + col) ^ ((row & 7) << 2)] = xr[rr];
        }
    }
    __syncthreads();

    // ---- store x_recon (nontemporal, coalesced) ----
    for (int i = t; i < 32 * 128; i += 512) {
        int d = i >> 5, r = i & 31;
        __builtin_nontemporal_store(wf[((r << 7) + d) ^ ((r & 7) << 2)],
                                    &outr[((bb * 128 + d) << 10) + hw0 + r]);
    }
}

extern "C" void kernel_launch(void* const* d_in, const int* in_sizes, int n_in,
                              void* d_out, int out_size, void* d_ws, size_t ws_size,
                              hipStream_t stream)
{
    const float* x     = (const float*)d_in[0];
    const float* Dict  = (const float*)d_in[1];
    const float* alpha = (const float*)d_in[2];
    const float* Lp    = (const float*)d_in[3];
    const int*   nip   = (const int*)d_in[4];

    float* outz = (float*)d_out;                 // [32,512,32,32]
    float* outr = outz + 32 * 512 * 1024;        // [32,128,32,32]
    float* outd = outr + 32 * 128 * 1024;        // [128,512]

    u16* Dnegb = (u16*)d_ws;                     // 128*512 bf16 = -Dict
    u16* DictT = Dnegb + 128 * 512;              // 512*128 bf16 = Dict^T

    prep_dict<<<dim3(256), dim3(256), 0, stream>>>(Dict, outd, Dnegb, DictT);
    lista_main<<<dim3(1024), dim3(512), 0, stream>>>(x, alpha, Lp, nip,
                                                     Dnegb, DictT, outz, outr);
}

// Round 7
// 207.164 us; speedup vs baseline: 8.7410x; 8.7410x over previous
//
#include <hip/hip_runtime.h>
#include <hip/hip_bf16.h>

typedef __bf16 bf16_t;
typedef bf16_t bf16x8 __attribute__((ext_vector_type(8)));
typedef float f32x4 __attribute__((ext_vector_type(4)));
typedef unsigned short u16;
typedef unsigned int u32;

static __device__ __forceinline__ u16 f2bf(float f) {
    __hip_bfloat16 h = __float2bfloat16(f);
    return __builtin_bit_cast(u16, h);
}
// float -> __bf16 with RNE via bit-cast (NOT integer conversion!)
static __device__ __forceinline__ bf16_t fb(float f) {
    return __builtin_bit_cast(bf16_t, f2bf(f));
}
static __device__ __forceinline__ float bf2f(u16 u) {
    u32 x = ((u32)u) << 16;
    return __builtin_bit_cast(float, x);
}
static __device__ __forceinline__ float softthr(float v, float l) {
    return copysignf(fmaxf(fabsf(v) - l, 0.0f), v);
}

// trivial: Dict copy to out[2]
__global__ __launch_bounds__(256) void copy_dict(const float* __restrict__ Dict,
                                                 float* __restrict__ outd)
{
    int i = blockIdx.x * 256 + threadIdx.x;   // 65536 total
    outd[i] = Dict[i];
}

// ---- fused LISTA, rank-128 factored, operand-swapped, dict-in-registers ----
// z_{t+1} = ST( z_t + (x - z_t @ D^T) @ D / L ),  z_0 = ST(x @ D)
// All C matrices transposed (m = dim/atom rows, n = pixel cols) so the dict
// is the A operand: per-wave-private, row-contiguous, held in VGPRs.
//  G1: a1[dim][px]  = x^T + (-D) @ z^T     (K=512 atoms)   16 dims/wave
//  G2: accz[atom][px] += D^T @ r^T          (K=128 dims)    64 atoms/wave
// accz (fp32 registers) IS z — never rounded across iterations.
// Inner loop touches ONLY LDS (zl 32KB, rl 8KB) and registers.
__global__ __launch_bounds__(512, 2)
void lista_main(const float* __restrict__ x,
                const float* __restrict__ Dict,    // fp32 [128][512]
                const float* __restrict__ alpha,
                const float* __restrict__ Lp,
                const int* __restrict__ nip,
                float* __restrict__ outz,          // [32][512][1024]
                float* __restrict__ outr)          // [32][128][1024]
{
    __shared__ __align__(16) u16 zl[32 * 512];   // z bf16 [px][atom], swizzled
    __shared__ __align__(16) u16 rl[32 * 128];   // r bf16 [px][dim],  swizzled

    const int t = threadIdx.x;
    const int lane = t & 63;
    const int l15 = lane & 15;
    const int lg = lane >> 4;            // 0..3
    const int wave = t >> 6;             // 0..7
    const int bb = blockIdx.x >> 5;             // batch
    const int hw0 = (blockIdx.x & 31) << 5;     // 32-pixel base
    const float invL = 1.0f / Lp[0];
    const int niter = nip[0];

    const int dimb = wave << 4;          // G1: 16 dims per wave
    const int atb  = wave << 6;          // G2: 64 atoms per wave

    // ---- stage rl = bf16(x) [px][dim] (iter-0 G2 B operand, unscaled) ----
    for (int i = t; i < 32 * 128; i += 512) {
        int d = i >> 5, px = i & 31;
        float v = x[((bb * 128 + d) << 10) + hw0 + px];
        rl[((px << 7) + d) ^ ((px & 7) << 3)] = f2bf(v);
    }

    // ---- x fp32 at G1 C positions: dim = dimb+lg*4+rr, px = nt*16+l15 ----
    float xpk[2][4];
#pragma unroll
    for (int nt = 0; nt < 2; ++nt)
#pragma unroll
        for (int rr = 0; rr < 4; ++rr)
            xpk[nt][rr] = x[((bb * 128 + dimb + lg * 4 + rr) << 10) + hw0 + nt * 16 + l15];

    // ---- thresholds at G2 C positions: one per n-tile (px = col) ----
    float thr[2];
#pragma unroll
    for (int nt = 0; nt < 2; ++nt)
        thr[nt] = alpha[hw0 + nt * 16 + l15] * invL;

    // ---- dict fragments -> registers (once) ----
    // G1 A: -Dict[dimb+l15][kt*32 + lg*8 + j]   (row-contiguous, float4 x2)
    bf16x8 g1a[16];
    {
        const float* drow = Dict + ((dimb + l15) << 9);
#pragma unroll
        for (int kt = 0; kt < 16; ++kt) {
            f32x4 c0 = *reinterpret_cast<const f32x4*>(&drow[kt * 32 + lg * 8]);
            f32x4 c1 = *reinterpret_cast<const f32x4*>(&drow[kt * 32 + lg * 8 + 4]);
#pragma unroll
            for (int j = 0; j < 4; ++j) {
                g1a[kt][j] = fb(-c0[j]);
                g1a[kt][j + 4] = fb(-c1[j]);
            }
        }
    }
    // G2 A: Dict^T[atb+at*16+l15][kt*32 + lg*8 + j] = Dict[dim][atom] gather
    bf16x8 g2a[4][4];
#pragma unroll
    for (int at = 0; at < 4; ++at)
#pragma unroll
        for (int kt = 0; kt < 4; ++kt)
#pragma unroll
            for (int j = 0; j < 8; ++j)
                g2a[at][kt][j] = fb(Dict[((kt * 32 + lg * 8 + j) << 9) + atb + at * 16 + l15]);

    __syncthreads();

    // G1: a1 = x^T + (-D) @ z^T   (reads all of zl)
    auto run_g1 = [&](f32x4 (&a1)[2]) {
#pragma unroll
        for (int nt = 0; nt < 2; ++nt) {
            a1[nt][0] = xpk[nt][0];
            a1[nt][1] = xpk[nt][1];
            a1[nt][2] = xpk[nt][2];
            a1[nt][3] = xpk[nt][3];
        }
#pragma unroll
        for (int kt = 0; kt < 16; ++kt) {
            bf16x8 Bf[2];
#pragma unroll
            for (int nt = 0; nt < 2; ++nt) {
                int px = nt * 16 + l15;
                Bf[nt] = *reinterpret_cast<const bf16x8*>(
                    &zl[((px << 9) + kt * 32 + lg * 8) ^ ((px & 7) << 3)]);
            }
#pragma unroll
            for (int nt = 0; nt < 2; ++nt)
                a1[nt] = __builtin_amdgcn_mfma_f32_16x16x32_bf16(g1a[kt], Bf[nt], a1[nt], 0, 0, 0);
        }
    };

    f32x4 accz[4][2];
#pragma unroll
    for (int at = 0; at < 4; ++at)
#pragma unroll
        for (int nt = 0; nt < 2; ++nt)
            accz[at][nt] = f32x4{0.f, 0.f, 0.f, 0.f};

    for (int it = 0; it <= niter; ++it) {
        if (it > 0) {
            f32x4 a1[2];
            run_g1(a1);
            // r = a1 * invL -> rl (4 consecutive dims per lane = one b64)
#pragma unroll
            for (int nt = 0; nt < 2; ++nt) {
                int px = nt * 16 + l15;
                uint2 pk;
                pk.x = (u32)f2bf(a1[nt][0] * invL) | ((u32)f2bf(a1[nt][1] * invL) << 16);
                pk.y = (u32)f2bf(a1[nt][2] * invL) | ((u32)f2bf(a1[nt][3] * invL) << 16);
                *reinterpret_cast<uint2*>(
                    &rl[((px << 7) + dimb + lg * 4) ^ ((px & 7) << 3)]) = pk;
            }
            __syncthreads();   // rl complete; all zl reads done
        }

        // ---- G2: accz += D^T @ r^T  (K=128, all operands reg/LDS) ----
#pragma unroll
        for (int kt = 0; kt < 4; ++kt) {
            bf16x8 Bf[2];
#pragma unroll
            for (int nt = 0; nt < 2; ++nt) {
                int px = nt * 16 + l15;
                Bf[nt] = *reinterpret_cast<const bf16x8*>(
                    &rl[((px << 7) + kt * 32 + lg * 8) ^ ((px & 7) << 3)]);
            }
            __builtin_amdgcn_s_setprio(1);
#pragma unroll
            for (int at = 0; at < 4; ++at)
#pragma unroll
                for (int nt = 0; nt < 2; ++nt)
                    accz[at][nt] = __builtin_amdgcn_mfma_f32_16x16x32_bf16(
                        g2a[at][kt], Bf[nt], accz[at][nt], 0, 0, 0);
            __builtin_amdgcn_s_setprio(0);
        }

        // ---- soft-threshold in place; write z bf16 to zl (b64 per frag) ----
#pragma unroll
        for (int at = 0; at < 4; ++at)
#pragma unroll
            for (int nt = 0; nt < 2; ++nt) {
                int px = nt * 16 + l15;
                f32x4 a = accz[at][nt];
                a[0] = softthr(a[0], thr[nt]);
                a[1] = softthr(a[1], thr[nt]);
                a[2] = softthr(a[2], thr[nt]);
                a[3] = softthr(a[3], thr[nt]);
                accz[at][nt] = a;
                uint2 pk;
                pk.x = (u32)f2bf(a[0]) | ((u32)f2bf(a[1]) << 16);
                pk.y = (u32)f2bf(a[2]) | ((u32)f2bf(a[3]) << 16);
                *reinterpret_cast<uint2*>(
                    &zl[((px << 9) + atb + at * 16 + lg * 4) ^ ((px & 7) << 3)]) = pk;
            }
        __syncthreads();   // zl ready for next G1 (rl free)
    }

    // ---- final G1: x_recon = x - a1 = z @ D^T ----
    f32x4 a1[2];
    run_g1(a1);

    // ---- store z from zl (nontemporal, coalesced 128B segments) ----
    for (int i = t; i < 32 * 512; i += 512) {
        int a = i >> 5, px = i & 31;
        float zv = bf2f(zl[((px << 9) + a) ^ ((px & 7) << 3)]);
        __builtin_nontemporal_store(zv, &outz[((bb * 512 + a) << 10) + hw0 + px]);
    }
    __syncthreads();   // zl reads done before overwrite

    // ---- stage x_recon fp32 [px][dim] swizzled in zl front (16 KB) ----
    float* wf = reinterpret_cast<float*>(zl);
#pragma unroll
    for (int nt = 0; nt < 2; ++nt) {
        int px = nt * 16 + l15;
#pragma unroll
        for (int rr = 0; rr < 4; ++rr)
            wf[((px << 7) + dimb + lg * 4 + rr) ^ ((px & 7) << 2)] = xpk[nt][rr] - a1[nt][rr];
    }
    __syncthreads();

    // ---- store x_recon (nontemporal, coalesced) ----
    for (int i = t; i < 32 * 128; i += 512) {
        int d = i >> 5, px = i & 31;
        __builtin_nontemporal_store(wf[((px << 7) + d) ^ ((px & 7) << 2)],
                                    &outr[((bb * 128 + d) << 10) + hw0 + px]);
    }
}

extern "C" void kernel_launch(void* const* d_in, const int* in_sizes, int n_in,
                              void* d_out, int out_size, void* d_ws, size_t ws_size,
                              hipStream_t stream)
{
    const float* x     = (const float*)d_in[0];
    const float* Dict  = (const float*)d_in[1];
    const float* alpha = (const float*)d_in[2];
    const float* Lp    = (const float*)d_in[3];
    const int*   nip   = (const int*)d_in[4];

    float* outz = (float*)d_out;                 // [32,512,32,32]
    float* outr = outz + 32 * 512 * 1024;        // [32,128,32,32]
    float* outd = outr + 32 * 128 * 1024;        // [128,512]

    copy_dict<<<dim3(256), dim3(256), 0, stream>>>(Dict, outd);
    lista_main<<<dim3(1024), dim3(512), 0, stream>>>(x, Dict, alpha, Lp, nip,
                                                     outz, outr);
}